// Round 3
// baseline (9042.957 us; speedup 1.0000x reference)
//
#include <hip/hip_runtime.h>
#include <hip/hip_bf16.h>

// ---------------------------------------------------------------------------
// Stacked BiLSTM (B=64, T=512, E=300, H=512, 2 layers) for MI355X / gfx950.
//
//   1. Convert embeddings + weights to bf16 (weights transposed to [n][k]).
//   2. Zx = X @ Wx + b for both directions fused (bf16 MFMA GEMM, N=4096).
//   3. Persistent recurrence kernel: 64 WGs (2 dirs x 32 hidden-slices),
//      Wh slice resident in LDS (XOR-swizzled), h exchanged via ping-pong
//      global bf16 buffer, custom device-scope barrier per step per dir
//      (with a finite spin budget so a lost WG cannot hang the GPU).
//   4. Repeat for layer 1 (K=1024), final h written fp32 to d_out.
//
// Workspace discipline: H0 (bf16 inter-layer activations) and X16 (bf16
// embeddings) live inside d_out's 134 MB; d_ws only holds Zx (256 MB) +
// weights (~19 MB) + h ping-pong + barrier counters (~283 MB total).
// ---------------------------------------------------------------------------

#define Bsz 64
#define Tsz 512
#define Esz 300
#define Hsz 512
#define BT  32768          // B*T
#define K0P 320            // E padded to multiple of 64
#define K1  1024           // 2H
#define NG  2048           // 4H gate cols per direction
#define NB  4096           // both directions fused

typedef unsigned short ushort_t;
typedef unsigned int   uint_t;
typedef short  short8  __attribute__((ext_vector_type(8)));   // 8 bf16 bits
typedef float  f32x4   __attribute__((ext_vector_type(4)));

__device__ __forceinline__ f32x4 mfma16(short8 a, short8 b, f32x4 c) {
  return __builtin_amdgcn_mfma_f32_16x16x32_bf16(a, b, c, 0, 0, 0);
}

__device__ __forceinline__ ushort_t f2bf(float f) {
  union { float f; uint_t u; } v; v.f = f;
  uint_t r = v.u + 0x7fffu + ((v.u >> 16) & 1u);   // RNE
  return (ushort_t)(r >> 16);
}
__device__ __forceinline__ float bf2f(ushort_t s) {
  union { uint_t u; float f; } v; v.u = ((uint_t)s) << 16;
  return v.f;
}
__device__ __forceinline__ float sigm(float x) { return 1.0f / (1.0f + __expf(-x)); }

// ---------------------------------------------------------------------------
// Embeddings fp32 [BT][300] -> bf16 [BT][320] (zero-padded K)
// ---------------------------------------------------------------------------
__global__ void conv_x(const float* __restrict__ x, ushort_t* __restrict__ out) {
  int idx = blockIdx.x * 256 + threadIdx.x;        // over BT*K0P
  int bt = idx / K0P;
  int k  = idx - bt * K0P;
  out[idx] = (k < Esz) ? f2bf(x[(size_t)bt * Esz + k]) : (ushort_t)0;
}

// ---------------------------------------------------------------------------
// Weight transpose+convert: out[n][k] = bf16(w[(krow0+k)*ldw + n]), k>=kvalid -> 0
// grid: (kpad/32, ncols/32), block: (32,8)
// ---------------------------------------------------------------------------
__global__ void transpose_conv(const float* __restrict__ w, int ldw, int krow0,
                               int kvalid, int kpad, ushort_t* __restrict__ out) {
  __shared__ float tile[32][33];
  int kb = blockIdx.x * 32, nb = blockIdx.y * 32;
  int tx = threadIdx.x, ty = threadIdx.y;
#pragma unroll
  for (int tt = 0; tt < 4; ++tt) {
    int k = kb + ty + tt * 8;
    float v = 0.0f;
    if (k < kvalid) v = w[(size_t)(krow0 + k) * ldw + nb + tx];
    tile[ty + tt * 8][tx] = v;
  }
  __syncthreads();
#pragma unroll
  for (int tt = 0; tt < 4; ++tt) {
    int n = nb + ty + tt * 8;
    int k = kb + tx;
    out[(size_t)n * kpad + k] = f2bf(tile[tx][ty + tt * 8]);
  }
}

// ---------------------------------------------------------------------------
// GEMM: C[m][n] = sum_k A[m][k]*Bt[n][k] + bias[n], bf16 in, bf16 out.
// M=BT, N=4096, K multiple of 64. 128x128 tile, 4 waves (2x2), BK=64.
// A/B LDS tiles XOR-swizzled ((row&7)<<3 ushorts) -> conflict-free ds_read_b128.
// ---------------------------------------------------------------------------
#define BKg 64
__global__ void __launch_bounds__(256) gemm_bt(
    const ushort_t* __restrict__ A, const ushort_t* __restrict__ Bt,
    const float* __restrict__ bias_fw, const float* __restrict__ bias_bw,
    ushort_t* __restrict__ C, int K) {
  __shared__ __align__(16) ushort_t lA[128 * BKg];
  __shared__ __align__(16) ushort_t lB[128 * BKg];
  int t  = threadIdx.x;
  int m0 = blockIdx.y * 128, n0 = blockIdx.x * 128;
  int w  = t >> 6, l = t & 63;
  int wm = (w >> 1) * 64, wn = (w & 1) * 64;
  int r  = t >> 1, hh = t & 1;                 // staging: row, which 32-col half
  int lrow = l & 15, lk8 = (l >> 4) * 8;

  f32x4 acc[4][4];
#pragma unroll
  for (int a = 0; a < 4; ++a)
#pragma unroll
    for (int b = 0; b < 4; ++b) acc[a][b] = f32x4{0.f, 0.f, 0.f, 0.f};

  const ushort_t* Ar = A + (size_t)(m0 + r) * K + hh * 32;
  const ushort_t* Br = Bt + (size_t)(n0 + r) * K + hh * 32;

  short8 sa[4], sb[4];
#pragma unroll
  for (int i = 0; i < 4; ++i) {
    sa[i] = *(const short8*)(Ar + i * 8);
    sb[i] = *(const short8*)(Br + i * 8);
  }

  int nk = K / BKg;
  int wr = r * BKg;
  int sw = (r & 7) << 3;                        // ushort-granule swizzle
  for (int kb = 0; kb < nk; ++kb) {
    __syncthreads();                            // prev iter LDS reads done
#pragma unroll
    for (int i = 0; i < 4; ++i) {
      *(short8*)(lA + wr + ((hh * 32 + i * 8) ^ sw)) = sa[i];
      *(short8*)(lB + wr + ((hh * 32 + i * 8) ^ sw)) = sb[i];
    }
    __syncthreads();
    if (kb + 1 < nk) {
#pragma unroll
      for (int i = 0; i < 4; ++i) {
        sa[i] = *(const short8*)(Ar + (kb + 1) * BKg + i * 8);
        sb[i] = *(const short8*)(Br + (kb + 1) * BKg + i * 8);
      }
    }
#pragma unroll
    for (int kq = 0; kq < 2; ++kq) {
      short8 af[4], bf_[4];
      int kk = kq * 32 + lk8;
#pragma unroll
      for (int ms = 0; ms < 4; ++ms) {
        int row = wm + ms * 16 + lrow;
        af[ms] = *(const short8*)(lA + row * BKg + (kk ^ ((row & 7) << 3)));
      }
#pragma unroll
      for (int ns = 0; ns < 4; ++ns) {
        int row = wn + ns * 16 + lrow;
        bf_[ns] = *(const short8*)(lB + row * BKg + (kk ^ ((row & 7) << 3)));
      }
#pragma unroll
      for (int ms = 0; ms < 4; ++ms)
#pragma unroll
        for (int ns = 0; ns < 4; ++ns)
          acc[ms][ns] = mfma16(af[ms], bf_[ns], acc[ms][ns]);
    }
  }
  // epilogue: D[row=(l>>4)*4+i][col=l&15]
#pragma unroll
  for (int ns = 0; ns < 4; ++ns) {
    int colg = n0 + wn + ns * 16 + lrow;
    float bv = (colg < NG) ? bias_fw[colg] : bias_bw[colg - NG];
#pragma unroll
    for (int ms = 0; ms < 4; ++ms) {
      int rowg = m0 + wm + ms * 16 + (l >> 4) * 4;
#pragma unroll
      for (int i = 0; i < 4; ++i)
        C[(size_t)(rowg + i) * NB + colg] = f2bf(acc[ms][ns][i] + bv);
    }
  }
}

// ---------------------------------------------------------------------------
// Persistent BiLSTM recurrence. Grid = 64 WGs x 256 thr.
//   blockIdx: dir = bid>>5 (0=fw,1=bw), p = bid&31 (hidden slice of 16 dims).
//   WG holds Wh columns {g*512 + p*16 + s : g in 0..3, s in 0..15} in LDS
//   as 64 rows x 512 k (bf16, XOR-swizzled). Each step:
//     z_rec[64 batch][64 gatecols] = h_prev[64][512] @ Wslice  (MFMA)
//     lane-local gates -> c,h update -> publish h slice -> 32-WG barrier.
// ---------------------------------------------------------------------------
#define PSLC 32
__global__ void __launch_bounds__(256, 1) lstm_rec(
    const ushort_t* __restrict__ Zx,    // [BT][4096] bf16 (bias folded in)
    const ushort_t* __restrict__ Wht,   // [2][2048][512] bf16
    const int* __restrict__ lens,       // [64]
    ushort_t* __restrict__ hbuf,        // [2 dir][2 pp][64][512] bf16 (pp zeroed)
    ushort_t* __restrict__ out16,       // H0 bf16 [BT][1024] (layer 0) or unused
    float* __restrict__ out32,          // d_out fp32 [BT][1024] (layer 1) or null
    uint_t* __restrict__ bar)           // [2 dir][512] zeroed counters
{
  int t = threadIdx.x;
  int dir = blockIdx.x >> 5, p = blockIdx.x & 31;
  int w = t >> 6, l = t & 63;
  int lrow = l & 15, lq = l >> 4;
  const int dimg = p * 16 + lrow;        // global hidden dim of this lane's col

  __shared__ __align__(16) ushort_t wl[64 * 512];   // 64 KB
  {
    int r = t >> 2, q = t & 3;           // row r (=g*16+s), quarter q
    int gcol = (r >> 4) * 512 + p * 16 + (r & 15);
    const ushort_t* src = Wht + ((size_t)dir * NG + gcol) * 512 + q * 128;
    int sw = (r & 7) << 3;
#pragma unroll
    for (int i = 0; i < 16; ++i)
      *(short8*)(wl + r * 512 + ((q * 128 + i * 8) ^ sw)) = *(const short8*)(src + i * 8);
  }
  int lens_r[4];
#pragma unroll
  for (int i = 0; i < 4; ++i) lens_r[i] = lens[w * 16 + lq * 4 + i];
  __syncthreads();

  float    c[4]   = {0.f, 0.f, 0.f, 0.f};
  ushort_t hmy[4] = {0, 0, 0, 0};
  uint_t* mybar = bar + dir * 512;
  int budget = 50000000;                  // finite spin budget: no GPU hang

  for (int s = 0; s < Tsz; ++s) {
    const ushort_t* hb = hbuf + ((size_t)(dir * 2 + (s & 1)) * 64) * 512;
    ushort_t*       hw = hbuf + ((size_t)(dir * 2 + ((s & 1) ^ 1)) * 64) * 512;

    // ---- prefetch Zx for this step (independent of h) ----
    int  ttc[4]; bool vld[4]; float zx[4][4];
#pragma unroll
    for (int i = 0; i < 4; ++i) {
      int brow = w * 16 + lq * 4 + i;
      vld[i] = (s < lens_r[i]);
      int tt = dir ? (lens_r[i] - 1 - s) : s;
      if (!vld[i]) tt = 0;
      ttc[i] = tt;
      const ushort_t* zrow = Zx + ((size_t)brow * Tsz + tt) * NB + dir * NG + dimg;
#pragma unroll
      for (int g = 0; g < 4; ++g) zx[i][g] = bf2f(zrow[g * 512]);
    }

    // ---- z_rec = h_prev @ Wslice ----
    f32x4 acc[4];
#pragma unroll
    for (int g = 0; g < 4; ++g) acc[g] = f32x4{0.f, 0.f, 0.f, 0.f};
#pragma unroll
    for (int kt = 0; kt < 16; ++kt) {
      short8 a = *(const short8*)(hb + (w * 16 + lrow) * 512 + kt * 32 + lq * 8);
#pragma unroll
      for (int g = 0; g < 4; ++g) {
        int row = g * 16 + lrow;
        short8 b = *(const short8*)(wl + row * 512 + ((kt * 32 + lq * 8) ^ ((row & 7) << 3)));
        acc[g] = mfma16(a, b, acc[g]);
      }
    }

    // ---- lane-local LSTM update: D row = w*16 + lq*4 + i, col dim = dimg ----
#pragma unroll
    for (int i = 0; i < 4; ++i) {
      int brow = w * 16 + lq * 4 + i;
      ushort_t hst = hmy[i];
      if (vld[i]) {
        float z0 = acc[0][i] + zx[i][0];   // i gate
        float z1 = acc[1][i] + zx[i][1];   // j (candidate)
        float z2 = acc[2][i] + zx[i][2];   // f gate
        float z3 = acc[3][i] + zx[i][3];   // o gate
        float ig = sigm(z0), jg = tanhf(z1), fg = sigm(z2 + 1.0f), og = sigm(z3);
        c[i] = fg * c[i] + ig * jg;
        float hn = og * tanhf(c[i]);
        hst = f2bf(hn);
        hmy[i] = hst;
        size_t oidx = ((size_t)brow * Tsz + ttc[i]) * 1024 + dir * 512 + dimg;
        if (out32) out32[oidx] = hn;
        else       out16[oidx] = hst;
      }
      hw[brow * 512 + dimg] = hst;   // always publish (frozen value if invalid)
    }

    // ---- 32-WG per-direction barrier (device scope, cross-XCD safe) ----
    __syncthreads();
    if (t == 0) {
      __builtin_amdgcn_fence(__ATOMIC_RELEASE, "agent");
      atomicAdd(&mybar[s], 1u);
      while (__hip_atomic_load(&mybar[s], __ATOMIC_RELAXED, __HIP_MEMORY_SCOPE_AGENT) < PSLC) {
        __builtin_amdgcn_s_sleep(2);
        if (--budget < 0) break;               // degrade to wrong-but-finite
      }
      __builtin_amdgcn_fence(__ATOMIC_ACQUIRE, "agent");
    }
    __syncthreads();
  }
}

// ---------------------------------------------------------------------------
extern "C" void kernel_launch(void* const* d_in, const int* in_sizes, int n_in,
                              void* d_out, int out_size, void* d_ws, size_t ws_size,
                              hipStream_t stream) {
  (void)in_sizes; (void)n_in; (void)ws_size;
  const float* emb    = (const float*)d_in[0];
  const int*   nwords = (const int*)d_in[1];
  const float* Wf0 = (const float*)d_in[2];
  const float* bf0 = (const float*)d_in[3];
  const float* Wb0 = (const float*)d_in[4];
  const float* bb0 = (const float*)d_in[5];
  const float* Wf1 = (const float*)d_in[6];
  const float* bf1 = (const float*)d_in[7];
  const float* Wb1 = (const float*)d_in[8];
  const float* bb1 = (const float*)d_in[9];

  // ---- carve d_out (134 MB): H0 bf16 (64 MB) + X16 bf16 (20 MB) ----
  ushort_t* H0  = (ushort_t*)d_out;                                   // BT*1024 bf16
  ushort_t* X16 = (ushort_t*)((char*)d_out + (size_t)BT * 1024 * 2);  // BT*320 bf16

  // ---- carve d_ws (~283 MB) ----
  char* ws = (char*)d_ws;
  size_t off = 0;
  auto alloc = [&](size_t bytes) {
    char* pp = ws + off;
    off += (bytes + 255) & ~(size_t)255;
    return pp;
  };
  ushort_t* W0xt = (ushort_t*)alloc((size_t)NB * K0P * 2);         // 2.6 MB
  ushort_t* W0ht = (ushort_t*)alloc((size_t)2 * NG * 512 * 2);     //   4 MB
  ushort_t* W1xt = (ushort_t*)alloc((size_t)NB * K1 * 2);          //  16 MB
  ushort_t* W1ht = (ushort_t*)alloc((size_t)2 * NG * 512 * 2);     //   4 MB
  ushort_t* Zx   = (ushort_t*)alloc((size_t)BT * NB * 2);          // 256 MB
  ushort_t* hbuf = (ushort_t*)alloc((size_t)2 * 2 * 64 * 512 * 2); // 256 KB
  uint_t*   bar  = (uint_t*)alloc((size_t)2 * 2 * 512 * 4);        //   8 KB

  // ---- zero-init (also clears harness 0xAA poison each replay) ----
  hipMemsetAsync(d_out, 0, (size_t)out_size * 4, stream);
  hipMemsetAsync(hbuf, 0, (size_t)2 * 2 * 64 * 512 * 2, stream);
  hipMemsetAsync(bar,  0, (size_t)2 * 2 * 512 * 4, stream);

  // ---- converts / transposes ----
  conv_x<<<dim3(BT * K0P / 256), 256, 0, stream>>>(emb, X16);
  transpose_conv<<<dim3(K0P / 32, 64), dim3(32, 8), 0, stream>>>(Wf0, NG, 0,    Esz,  K0P, W0xt);
  transpose_conv<<<dim3(K0P / 32, 64), dim3(32, 8), 0, stream>>>(Wb0, NG, 0,    Esz,  K0P, W0xt + (size_t)NG * K0P);
  transpose_conv<<<dim3(512 / 32, 64), dim3(32, 8), 0, stream>>>(Wf0, NG, Esz,  512,  512, W0ht);
  transpose_conv<<<dim3(512 / 32, 64), dim3(32, 8), 0, stream>>>(Wb0, NG, Esz,  512,  512, W0ht + (size_t)NG * 512);
  transpose_conv<<<dim3(K1 / 32, 64),  dim3(32, 8), 0, stream>>>(Wf1, NG, 0,    K1,   K1,  W1xt);
  transpose_conv<<<dim3(K1 / 32, 64),  dim3(32, 8), 0, stream>>>(Wb1, NG, 0,    K1,   K1,  W1xt + (size_t)NG * K1);
  transpose_conv<<<dim3(512 / 32, 64), dim3(32, 8), 0, stream>>>(Wf1, NG, K1,   512,  512, W1ht);
  transpose_conv<<<dim3(512 / 32, 64), dim3(32, 8), 0, stream>>>(Wb1, NG, K1,   512,  512, W1ht + (size_t)NG * 512);

  // ---- layer 0 ----
  gemm_bt<<<dim3(NB / 128, BT / 128), 256, 0, stream>>>(X16, W0xt, bf0, bb0, Zx, K0P);
  lstm_rec<<<64, 256, 0, stream>>>(Zx, W0ht, nwords, hbuf, H0, nullptr, bar);

  hipMemsetAsync(hbuf, 0, (size_t)2 * 2 * 64 * 512 * 2, stream);

  // ---- layer 1 (reads H0 from d_out, then d_out is re-zeroed for output) ----
  gemm_bt<<<dim3(NB / 128, BT / 128), 256, 0, stream>>>(H0, W1xt, bf1, bb1, Zx, K1);
  hipMemsetAsync(d_out, 0, (size_t)out_size * 4, stream);
  lstm_rec<<<64, 256, 0, stream>>>(Zx, W1ht, nwords, hbuf, nullptr, (float*)d_out, bar + 1024);
}